// Round 16
// baseline (98.654 us; speedup 1.0000x reference)
//
#include <hip/hip_runtime.h>
#include <math.h>

// Problem constants (fixed by the reference setup)
constexpr int BB = 64, LL = 512, DD = 768, SS = 30;
constexpr int NDOMc = 5, NGATEc = 3, PRED = 2;

// Output layout (flat float32, reference return order)
constexpr size_t O_DOM   = 0;                               // (B,5)
constexpr size_t O_SPP   = O_DOM   + (size_t)BB*NDOMc;      // (B,30) sigmoid
constexpr size_t O_GATE  = O_SPP   + (size_t)BB*SS;         // (B,30,3) softmax
constexpr size_t O_SPTR  = O_GATE  + (size_t)BB*SS*NGATEc;  // (B,30) passthrough
constexpr size_t O_SGATE = O_SPTR  + (size_t)BB*SS;         // (B,30) passthrough
constexpr size_t O_SPROB = O_SGATE + (size_t)BB*SS;         // (B,30,512)
constexpr size_t O_EPROB = O_SPROB + (size_t)BB*SS*LL;      // (B,30,512)

// Workspace layout (floats): WgW[30*768*3], bgW[96], then ints
constexpr int WS_WGW = 0;
constexpr int WS_BGW = SS*DD*NGATEc;        // 69120
constexpr int WS_INT = WS_BGW + 96;         // 69216 (float offset where ints start)

constexpr int KB_ROWS = SS*DD + SS;         // 23070
constexpr int MAXW = 512;                   // items buffer (worst case)
constexpr int KB_BLOCKS = (KB_ROWS/2 + 3) / 4;            // 2884
// Score slot = (item w<256 [+wrap], 64-row block rb<8): 2048 slots.
// Grid pattern per 3 bids: {1 score, 2 kB}. Dead slots land in the tail.
constexpr int NG3 = 2048;
constexpr int GRID_BD = NG3 * 3;            // 6144

__device__ __forceinline__ float wred64(float v) {
    #pragma unroll
    for (int o = 32; o; o >>= 1) v += __shfl_xor(v, o);
    return v;
}

// ---------- Kernel A: per-batch small dots, passthrough, scan/compaction ----
__global__ __launch_bounds__(256) void kA(
    const float* __restrict__ cls, const float* __restrict__ Wdom,
    const float* __restrict__ bdom, const float* __restrict__ Wslot,
    const float* __restrict__ bslot, const int* __restrict__ sp,
    const int* __restrict__ sg, float* __restrict__ out,
    int* __restrict__ nptr, int* __restrict__ nsel,
    int* __restrict__ ptrpos, int* __restrict__ selpos)
{
    const int b = blockIdx.x;
    const int tid = threadIdx.x, lane = tid & 63, wid = tid >> 6;
    const float* c = cls + (size_t)b * DD;

    for (int t = wid; t < NDOMc + SS; t += 4) {
        float acc = 0.f;
        if (t < NDOMc) {
            for (int d = lane; d < DD; d += 64) acc += c[d] * Wdom[d*NDOMc + t];
        } else {
            const int j = t - NDOMc;
            for (int d = lane; d < DD; d += 64) acc += c[d] * Wslot[d*SS + j];
        }
        acc = wred64(acc);
        if (lane == 0) {
            if (t < NDOMc) out[O_DOM + (size_t)b*NDOMc + t] = acc + bdom[t];
            else {
                const int j = t - NDOMc;
                const float x = acc + bslot[j];
                out[O_SPP + (size_t)b*SS + j] = 1.f / (1.f + expf(-x));
            }
        }
    }
    if (tid < SS) {
        out[O_SPTR  + (size_t)b*SS + tid] = (float)sp[b*SS + tid];
        out[O_SGATE + (size_t)b*SS + tid] = (float)sg[b*SS + tid];
    }
    // serial scan: ptr ranks and pmask compaction.
    // NOTE: gate_at_slot = slot_gate[b, clip(csum-1,0,M-1)] -> indexed by RANK.
    // selpos padded with the last valid slot so kBD reads UNCONDITIONALLY.
    if (tid == 0) {
        int cp = 0, cs = 0;
        for (int i = 0; i < SS; ++i) {
            if (sp[b*SS + i] == 1) {
                const int rank = cp;            // csum-1 at this position
                ptrpos[b*SS + rank] = i;
                ++cp;
                if (sg[b*SS + rank] == PRED) { selpos[b*SS + cs] = i; ++cs; }
            }
        }
        nptr[b] = cp; nsel[b] = cs;
        const int last = (cs > 0) ? selpos[b*SS + cs - 1] : 0;
        for (int i = cs; i < SS; ++i) selpos[b*SS + i] = last;
    }
}

// ---------- Kernel A2: compact (b, 4-slot group) work items, sorted by b ----
__global__ __launch_bounds__(64) void kA2(
    const int* __restrict__ nsel, int* __restrict__ items, int* __restrict__ NW)
{
    const int lane = threadIdx.x;               // 1 wave, lane == b
    const int ns = nsel[lane];
    const int cnt = (ns + 3) >> 2;              // ceil(ns/4) items
    int off = cnt;
    #pragma unroll
    for (int d = 1; d < 64; d <<= 1) {          // inclusive scan
        const int t = __shfl_up(off, d);
        if (lane >= d) off += t;
    }
    off -= cnt;                                 // exclusive prefix
    for (int i = 0; i < cnt; ++i) items[off + i] = lane * SS + 4*i;
    if (lane == 63) *NW = off + cnt;
}

// ---------- fused kBD: 1 score + 2 kB per 3 bids; NO LDS, NO BARRIERS ------
// Score block: 64 rows x 8 cols (one 4-slot item). Lane-quad splits k 4-way:
// lane phase ph takes float4-chunks q = ph + 4t -> 64B-coalesced H reads.
// Combine = 2 shfl_xor within the quad. W via block-uniform pointers.
__global__ __launch_bounds__(256) void kBD(
    const float* __restrict__ H, const float* __restrict__ Ws,
    const float* __restrict__ We, const int* __restrict__ nsel,
    const int* __restrict__ selpos, float* __restrict__ out,
    const float* __restrict__ Wg, const float* __restrict__ bg,
    const float* __restrict__ Wgate,
    float* __restrict__ WgW, float* __restrict__ bgW,
    const int* __restrict__ items, const int* __restrict__ NW)
{
    const int bid = blockIdx.x;
    const int tid = threadIdx.x;
    const int g3 = bid / 3, r3 = bid % 3;

    if (r3 == 0) {
        // ---- score slot -----------------------------------------------------
        const int sb = g3;                      // 0..2047
        const int w0 = sb >> 3, rb = sb & 7;
        const int nw = *NW;
        const int ph = tid & 3;                 // k-phase within lane-quad
        const int row = rb * 64 + (tid >> 2);   // this thread's H row
        for (int w = w0; w < nw; w += 256) {    // executes once for NW<=256
            const int item = items[w];
            const int b = item / SS, k0 = item % SS;
            const int ns = nsel[b];

            const float4* __restrict__ h4 = (const float4*)(H + ((size_t)b * LL + row) * DD);
            const float4* pS[4]; const float4* pE[4];
            #pragma unroll
            for (int j = 0; j < 4; ++j) {
                int kk = k0 + j; if (kk > SS-1) kk = SS-1;
                const int s = selpos[b*SS + kk];
                pS[j] = (const float4*)(Ws + (size_t)s * DD);
                pE[j] = (const float4*)(We + (size_t)s * DD);
            }
            float4 aS[4], aE[4];
            #pragma unroll
            for (int j = 0; j < 4; ++j) {
                aS[j] = make_float4(0.f,0.f,0.f,0.f);
                aE[j] = make_float4(0.f,0.f,0.f,0.f);
            }
            #pragma unroll 2
            for (int t = 0; t < 48; ++t) {      // k-chunks q = ph + 4t
                const int q = ph + 4*t;
                const float4 h = h4[q];
                #pragma unroll
                for (int j = 0; j < 4; ++j) {
                    const float4 ws_ = pS[j][q];
                    const float4 we_ = pE[j][q];
                    aS[j].x += h.x*ws_.x; aS[j].y += h.y*ws_.y;
                    aS[j].z += h.z*ws_.z; aS[j].w += h.w*ws_.w;
                    aE[j].x += h.x*we_.x; aE[j].y += h.y*we_.y;
                    aE[j].z += h.z*we_.z; aE[j].w += h.w*we_.w;
                }
            }
            float sS[4], sE[4];
            #pragma unroll
            for (int j = 0; j < 4; ++j) {       // fold + quad-combine
                float s = (aS[j].x + aS[j].y) + (aS[j].z + aS[j].w);
                float e = (aE[j].x + aE[j].y) + (aE[j].z + aE[j].w);
                s += __shfl_xor(s, 1); s += __shfl_xor(s, 2);
                e += __shfl_xor(e, 1); e += __shfl_xor(e, 2);
                sS[j] = s; sE[j] = e;
            }
            const int ka = k0 + ph;             // lane ph stores slot ph
            if (ka < ns) {
                const float vs = (ph==0)?sS[0]:(ph==1)?sS[1]:(ph==2)?sS[2]:sS[3];
                const float ve = (ph==0)?sE[0]:(ph==1)?sE[1]:(ph==2)?sE[2]:sE[3];
                out[O_SPROB + (size_t)(b*SS + ka) * LL + row] = vs;
                out[O_EPROB + (size_t)(b*SS + ka) * LL + row] = ve;
            }
        }
        return;
    }

    // ---- kB block: WgW precompute, 2 rows per wave; pure HBM stream --------
    const int kb = g3 * 2 + (r3 - 1);
    if (kb >= KB_BLOCKS) return;
    const int lane = tid & 63, wid = tid >> 6;
    const int r0 = (kb * 4 + wid) * 2;
    if (r0 >= KB_ROWS) return;

    float wgt[3][4][3];
    #pragma unroll
    for (int j = 0; j < 3; ++j)
        #pragma unroll
        for (int cc = 0; cc < 4; ++cc) {
            const int e = j*256 + lane*4 + cc;
            #pragma unroll
            for (int gg = 0; gg < NGATEc; ++gg) wgt[j][cc][gg] = Wgate[e*NGATEc + gg];
        }

    const float* src0 = (r0 < SS*DD) ? Wg + (size_t)r0*DD : bg + (size_t)(r0 - SS*DD)*DD;
    const int r1 = r0 + 1;
    const float* src1 = (r1 < SS*DD) ? Wg + (size_t)r1*DD : bg + (size_t)(r1 - SS*DD)*DD;
    float* dst0 = (r0 < SS*DD) ? WgW + (size_t)r0*3 : bgW + (r0 - SS*DD)*3;
    float* dst1 = (r1 < SS*DD) ? WgW + (size_t)r1*3 : bgW + (r1 - SS*DD)*3;

    const float4* s40 = (const float4*)src0;
    const float4* s41 = (const float4*)src1;
    float a0=0,a1=0,a2=0, c0=0,c1=0,c2=0;
    #pragma unroll
    for (int j = 0; j < 3; ++j) {
        const float4 v  = s40[j*64 + lane];
        const float4 w2 = s41[j*64 + lane];
        a0 += v.x*wgt[j][0][0] + v.y*wgt[j][1][0] + v.z*wgt[j][2][0] + v.w*wgt[j][3][0];
        a1 += v.x*wgt[j][0][1] + v.y*wgt[j][1][1] + v.z*wgt[j][2][1] + v.w*wgt[j][3][1];
        a2 += v.x*wgt[j][0][2] + v.y*wgt[j][1][2] + v.z*wgt[j][2][2] + v.w*wgt[j][3][2];
        c0 += w2.x*wgt[j][0][0] + w2.y*wgt[j][1][0] + w2.z*wgt[j][2][0] + w2.w*wgt[j][3][0];
        c1 += w2.x*wgt[j][0][1] + w2.y*wgt[j][1][1] + w2.z*wgt[j][2][1] + w2.w*wgt[j][3][1];
        c2 += w2.x*wgt[j][0][2] + w2.y*wgt[j][1][2] + w2.z*wgt[j][2][2] + w2.w*wgt[j][3][2];
    }
    a0 = wred64(a0); a1 = wred64(a1); a2 = wred64(a2);
    c0 = wred64(c0); c1 = wred64(c1); c2 = wred64(c2);
    if (lane == 0) {
        dst0[0] = a0; dst0[1] = a1; dst0[2] = a2;
        dst1[0] = c0; dst1[1] = c1; dst1[2] = c2;
    }
}

// ---------- Kernel C: slot_gate_prob ----------------------------------------
__global__ __launch_bounds__(256) void kC(
    const float* __restrict__ cls, const float* __restrict__ WgW,
    const float* __restrict__ bgW, const float* __restrict__ bgate,
    const int* __restrict__ nptr, const int* __restrict__ ptrpos,
    float* __restrict__ out)
{
    const int lane = threadIdx.x & 63, wid = threadIdx.x >> 6;
    const int idx = blockIdx.x * 4 + wid;       // b*SS + m
    if (idx >= BB*SS) return;
    const int b = idx / SS, m = idx % SS;

    float s0, s1, s2;
    if (m < nptr[b]) {
        const int s = ptrpos[b*SS + m];
        const float4* c4 = (const float4*)(cls + (size_t)b * DD);
        float a0 = 0.f, a1 = 0.f, a2 = 0.f;
        #pragma unroll
        for (int j = 0; j < 3; ++j) {
            const float4 v = c4[j*64 + lane];
            const float* wp = WgW + ((size_t)s*DD + j*256 + lane*4) * 3;
            a0 += v.x*wp[0] + v.y*wp[3] + v.z*wp[6] + v.w*wp[9];
            a1 += v.x*wp[1] + v.y*wp[4] + v.z*wp[7] + v.w*wp[10];
            a2 += v.x*wp[2] + v.y*wp[5] + v.z*wp[8] + v.w*wp[11];
        }
        a0 = wred64(a0); a1 = wred64(a1); a2 = wred64(a2);
        s0 = a0 + bgW[s*3+0] + bgate[0];
        s1 = a1 + bgW[s*3+1] + bgate[1];
        s2 = a2 + bgW[s*3+2] + bgate[2];
    } else {
        s0 = bgate[0]; s1 = bgate[1]; s2 = bgate[2];
    }
    if (lane == 0) {
        const float mx = fmaxf(s0, fmaxf(s1, s2));
        const float e0 = expf(s0 - mx), e1 = expf(s1 - mx), e2 = expf(s2 - mx);
        const float inv = 1.f / (e0 + e1 + e2);
        float* o = out + O_GATE + (size_t)idx * NGATEc;
        o[0] = e0*inv; o[1] = e1*inv; o[2] = e2*inv;
    }
}

// ---------- Kernel E: softmax in place over L=512 ---------------------------
__global__ __launch_bounds__(256) void kE(
    const int* __restrict__ nsel, float* __restrict__ out)
{
    const int idx = blockIdx.x;             // b*SS + k
    const int b = idx / SS, k = idx % SS;
    const int tid = threadIdx.x;
    float* outs = out + O_SPROB + (size_t)idx * LL;
    float* oute = out + O_EPROB + (size_t)idx * LL;

    if (k >= nsel[b]) {                     // softmax(zeros) = 1/L exactly
        const float u = 1.0f / LL;
        outs[tid] = u; outs[tid + 256] = u;
        oute[tid] = u; oute[tid + 256] = u;
        return;
    }
    const int lane = tid & 63, wid = tid >> 6;
    __shared__ float rmax[2][4], rsum[2][4];

    const float s0 = outs[tid], s1 = outs[tid + 256];
    const float t0 = oute[tid], t1 = oute[tid + 256];

    float ms = fmaxf(s0, s1), me = fmaxf(t0, t1);
    #pragma unroll
    for (int o = 32; o; o >>= 1) { ms = fmaxf(ms, __shfl_xor(ms, o)); me = fmaxf(me, __shfl_xor(me, o)); }
    if (lane == 0) { rmax[0][wid] = ms; rmax[1][wid] = me; }
    __syncthreads();
    ms = fmaxf(fmaxf(rmax[0][0], rmax[0][1]), fmaxf(rmax[0][2], rmax[0][3]));
    me = fmaxf(fmaxf(rmax[1][0], rmax[1][1]), fmaxf(rmax[1][2], rmax[1][3]));

    const float e0 = expf(s0 - ms), e1 = expf(s1 - ms);
    const float f0 = expf(t0 - me), f1 = expf(t1 - me);
    float sa = e0 + e1, sb = f0 + f1;
    #pragma unroll
    for (int o = 32; o; o >>= 1) { sa += __shfl_xor(sa, o); sb += __shfl_xor(sb, o); }
    if (lane == 0) { rsum[0][wid] = sa; rsum[1][wid] = sb; }
    __syncthreads();
    const float inva = 1.f / (rsum[0][0] + rsum[0][1] + rsum[0][2] + rsum[0][3]);
    const float invb = 1.f / (rsum[1][0] + rsum[1][1] + rsum[1][2] + rsum[1][3]);

    outs[tid] = e0 * inva; outs[tid + 256] = e1 * inva;
    oute[tid] = f0 * invb; oute[tid + 256] = f1 * invb;
}

extern "C" void kernel_launch(void* const* d_in, const int* in_sizes, int n_in,
                              void* d_out, int out_size, void* d_ws, size_t ws_size,
                              hipStream_t stream)
{
    const float* H      = (const float*)d_in[0];
    const float* cls    = (const float*)d_in[1];
    const float* Wdom   = (const float*)d_in[2];
    const float* bdom   = (const float*)d_in[3];
    const float* Wslot  = (const float*)d_in[4];
    const float* bslot  = (const float*)d_in[5];
    const float* Wg     = (const float*)d_in[6];
    const float* bg     = (const float*)d_in[7];
    const float* Wgate  = (const float*)d_in[8];
    const float* bgate  = (const float*)d_in[9];
    const float* Wstart = (const float*)d_in[10];
    // d_in[11] b_start: constant per softmax row -> softmax-invariant, unused
    const float* Wend   = (const float*)d_in[12];
    // d_in[13] b_end: unused (same reason)
    const int* sp = (const int*)d_in[14];
    const int* sg = (const int*)d_in[15];

    float* out = (float*)d_out;
    float* wsf = (float*)d_ws;
    float* WgW = wsf + WS_WGW;
    float* bgW = wsf + WS_BGW;
    int* ipart  = (int*)(wsf + WS_INT);
    int* nptr   = ipart;
    int* nsel   = ipart + 64;
    int* ptrpos = ipart + 128;
    int* selpos = ptrpos + BB*SS;
    int* items  = selpos + BB*SS;
    int* NW     = items + MAXW;

    kA<<<BB, 256, 0, stream>>>(cls, Wdom, bdom, Wslot, bslot, sp, sg, out,
                               nptr, nsel, ptrpos, selpos);
    kA2<<<1, 64, 0, stream>>>(nsel, items, NW);
    kBD<<<GRID_BD, 256, 0, stream>>>(H, Wstart, Wend, nsel, selpos, out,
                                     Wg, bg, Wgate, WgW, bgW, items, NW);
    kC<<<(BB*SS) / 4, 256, 0, stream>>>(cls, WgW, bgW, bgate, nptr, ptrpos, out);
    kE<<<BB * SS, 256, 0, stream>>>(nsel, out);
}

// Round 17
// 79.872 us; speedup vs baseline: 1.2351x; 1.2351x over previous
//
#include <hip/hip_runtime.h>
#include <math.h>

// Problem constants (fixed by the reference setup)
constexpr int BB = 64, LL = 512, DD = 768, SS = 30;
constexpr int NDOMc = 5, NGATEc = 3, PRED = 2;

// Output layout (flat float32, reference return order)
constexpr size_t O_DOM   = 0;                               // (B,5)
constexpr size_t O_SPP   = O_DOM   + (size_t)BB*NDOMc;      // (B,30) sigmoid
constexpr size_t O_GATE  = O_SPP   + (size_t)BB*SS;         // (B,30,3) softmax
constexpr size_t O_SPTR  = O_GATE  + (size_t)BB*SS*NGATEc;  // (B,30) passthrough
constexpr size_t O_SGATE = O_SPTR  + (size_t)BB*SS;         // (B,30) passthrough
constexpr size_t O_SPROB = O_SGATE + (size_t)BB*SS;         // (B,30,512)
constexpr size_t O_EPROB = O_SPROB + (size_t)BB*SS*LL;      // (B,30,512)

// Workspace layout: floats WgW[69120], bgW[96]; ushort Wb[64*768]; then ints
constexpr int WS_BGW = SS*DD*NGATEc;        // 69120
constexpr int WS_WB  = WS_BGW + 96;         // 69216 (float offset of Wb)
constexpr int WS_INT = WS_WB + (64*DD)/2;   // 69216 + 24576 = 93792

constexpr int KB_ROWS = SS*DD + SS;         // 23070
constexpr int KB_BLOCKS = (KB_ROWS/2 + 3) / 4;   // 2884
constexpr int GB = BB * 8;                  // 512 GEMM blocks (64 rows each)
constexpr int WBF = (64*DD) / 256;          // 192 Wb-fill blocks

typedef __attribute__((ext_vector_type(8))) short short8;
typedef __attribute__((ext_vector_type(4))) float f32x4;

__device__ __forceinline__ float wred64(float v) {
    #pragma unroll
    for (int o = 32; o; o >>= 1) v += __shfl_xor(v, o);
    return v;
}

// ---------- Kernel A: per-batch dots, passthrough, scan; + Wb bf16 fill -----
__global__ __launch_bounds__(256) void kA(
    const float* __restrict__ cls, const float* __restrict__ Wdom,
    const float* __restrict__ bdom, const float* __restrict__ Wslot,
    const float* __restrict__ bslot, const int* __restrict__ sp,
    const int* __restrict__ sg, float* __restrict__ out,
    int* __restrict__ nptr, int* __restrict__ nsel,
    int* __restrict__ ptrpos, int* __restrict__ selpos, int* __restrict__ s2r,
    const float* __restrict__ Ws, const float* __restrict__ We,
    ushort* __restrict__ Wb)
{
    const int bid = blockIdx.x;
    const int tid = threadIdx.x;
    if (bid >= BB) {
        // Wb fill: bf16 weights, layout [64 cols][768 k]; cols 30,31,62,63 = 0
        const int idx = (bid - BB) * 256 + tid;     // 0..49151
        const int c = idx / DD, k = idx - c * DD;
        float v = 0.f;
        if (c < 30) v = Ws[c*DD + k];
        else if (c >= 32 && c < 62) v = We[(c-32)*DD + k];
        uint32_t u = __float_as_uint(v);
        u += 0x7fff + ((u >> 16) & 1);              // RNE fp32->bf16
        Wb[idx] = (ushort)(u >> 16);
        return;
    }
    const int b = bid;
    const int lane = tid & 63, wid = tid >> 6;
    const float* c = cls + (size_t)b * DD;

    for (int t = wid; t < NDOMc + SS; t += 4) {
        float acc = 0.f;
        if (t < NDOMc) {
            for (int d = lane; d < DD; d += 64) acc += c[d] * Wdom[d*NDOMc + t];
        } else {
            const int j = t - NDOMc;
            for (int d = lane; d < DD; d += 64) acc += c[d] * Wslot[d*SS + j];
        }
        acc = wred64(acc);
        if (lane == 0) {
            if (t < NDOMc) out[O_DOM + (size_t)b*NDOMc + t] = acc + bdom[t];
            else {
                const int j = t - NDOMc;
                const float x = acc + bslot[j];
                out[O_SPP + (size_t)b*SS + j] = 1.f / (1.f + expf(-x));
            }
        }
    }
    if (tid < SS) {
        out[O_SPTR  + (size_t)b*SS + tid] = (float)sp[b*SS + tid];
        out[O_SGATE + (size_t)b*SS + tid] = (float)sg[b*SS + tid];
    }
    // serial scan: ptr ranks, pmask compaction, and slot->rank inverse map.
    // NOTE: gate_at_slot = slot_gate[b, clip(csum-1,0,M-1)] -> indexed by RANK.
    if (tid == 0) {
        for (int s = 0; s < SS; ++s) s2r[b*SS + s] = -1;
        int cp = 0, cs = 0;
        for (int i = 0; i < SS; ++i) {
            if (sp[b*SS + i] == 1) {
                const int rank = cp;            // csum-1 at this position
                ptrpos[b*SS + rank] = i;
                ++cp;
                if (sg[b*SS + rank] == PRED) {
                    selpos[b*SS + cs] = i;
                    s2r[b*SS + i] = cs;         // slot i -> rank cs
                    ++cs;
                }
            }
        }
        nptr[b] = cp; nsel[b] = cs;
    }
}

// ---------- fused kBG: MFMA score GEMM blocks, then WgW stream blocks -------
// GEMM: wave = 16 rows x 64 cols (4 col-tiles), 24 K-steps of 32.
// A = H rows fp32->bf16 in regs; B = Wb bf16 (L2-resident). Stores gather
// through s2r (slot->rank) into the exact rows kE softmaxes in place.
__global__ __launch_bounds__(256) void kBG(
    const float* __restrict__ H, const ushort* __restrict__ Wb,
    const int* __restrict__ nsel, const int* __restrict__ s2r,
    float* __restrict__ out,
    const float* __restrict__ Wg, const float* __restrict__ bg,
    const float* __restrict__ Wgate,
    float* __restrict__ WgW, float* __restrict__ bgW)
{
    const int bid = blockIdx.x;
    const int tid = threadIdx.x;

    if (bid < GB) {
        const int b = bid >> 3;
        if (nsel[b] == 0) return;               // kE fills uniform rows
        const int wid = tid >> 6, lane = tid & 63;
        const int rbase = (bid & 7) * 64 + wid * 16;
        const int mr = lane & 15, kg = lane >> 4;

        const float* hrow = H + ((size_t)b * LL + rbase + mr) * DD + kg * 8;
        const ushort* wb0 = Wb + (size_t)(mr) * DD + kg * 8;
        const ushort* wb1 = wb0 + 16 * DD;
        const ushort* wb2 = wb0 + 32 * DD;
        const ushort* wb3 = wb0 + 48 * DD;

        f32x4 acc0 = {0.f,0.f,0.f,0.f}, acc1 = acc0, acc2 = acc0, acc3 = acc0;

        #pragma unroll 4
        for (int ks = 0; ks < 24; ++ks) {
            const float4 a0 = *(const float4*)(hrow + ks*32);
            const float4 a1 = *(const float4*)(hrow + ks*32 + 4);
            short8 af;
            {
                const float av[8] = {a0.x,a0.y,a0.z,a0.w,a1.x,a1.y,a1.z,a1.w};
                #pragma unroll
                for (int i = 0; i < 8; ++i) {
                    uint32_t u = __float_as_uint(av[i]);
                    u += 0x7fff + ((u >> 16) & 1);  // RNE fp32->bf16
                    af[i] = (short)(u >> 16);
                }
            }
            const short8 b0 = *(const short8*)(wb0 + ks*32);
            const short8 b1 = *(const short8*)(wb1 + ks*32);
            const short8 b2 = *(const short8*)(wb2 + ks*32);
            const short8 b3 = *(const short8*)(wb3 + ks*32);
            acc0 = __builtin_amdgcn_mfma_f32_16x16x32_bf16(af, b0, acc0, 0,0,0);
            acc1 = __builtin_amdgcn_mfma_f32_16x16x32_bf16(af, b1, acc1, 0,0,0);
            acc2 = __builtin_amdgcn_mfma_f32_16x16x32_bf16(af, b2, acc2, 0,0,0);
            acc3 = __builtin_amdgcn_mfma_f32_16x16x32_bf16(af, b3, acc3, 0,0,0);
        }

        // C/D layout: col = lane&15, row = (lane>>4)*4 + reg  [m89-verified]
        const int row0 = rbase + kg * 4;
        #pragma unroll
        for (int ct = 0; ct < 4; ++ct) {
            const f32x4 a = (ct==0)?acc0:(ct==1)?acc1:(ct==2)?acc2:acc3;
            const int cc = ct*16 + mr;
            int slot; size_t ob;
            if (cc < 30)                  { slot = cc;      ob = O_SPROB; }
            else if (cc >= 32 && cc < 62) { slot = cc - 32; ob = O_EPROB; }
            else continue;
            const int r = s2r[b*SS + slot];
            if (r >= 0) {
                float4 v = make_float4(a[0], a[1], a[2], a[3]);
                *(float4*)(out + ob + ((size_t)(b*SS + r)) * LL + row0) = v;
            }
        }
        return;
    }

    // ---- kB block: WgW precompute, 2 rows per wave; pure HBM stream --------
    const int kb = bid - GB;
    if (kb >= KB_BLOCKS) return;
    const int lane = tid & 63, wid = tid >> 6;
    const int r0 = (kb * 4 + wid) * 2;
    if (r0 >= KB_ROWS) return;

    float wgt[3][4][3];
    #pragma unroll
    for (int j = 0; j < 3; ++j)
        #pragma unroll
        for (int cc = 0; cc < 4; ++cc) {
            const int e = j*256 + lane*4 + cc;
            #pragma unroll
            for (int gg = 0; gg < NGATEc; ++gg) wgt[j][cc][gg] = Wgate[e*NGATEc + gg];
        }

    const float* src0 = (r0 < SS*DD) ? Wg + (size_t)r0*DD : bg + (size_t)(r0 - SS*DD)*DD;
    const int r1 = r0 + 1;
    const float* src1 = (r1 < SS*DD) ? Wg + (size_t)r1*DD : bg + (size_t)(r1 - SS*DD)*DD;
    float* dst0 = (r0 < SS*DD) ? WgW + (size_t)r0*3 : bgW + (r0 - SS*DD)*3;
    float* dst1 = (r1 < SS*DD) ? WgW + (size_t)r1*3 : bgW + (r1 - SS*DD)*3;

    const float4* s40 = (const float4*)src0;
    const float4* s41 = (const float4*)src1;
    float a0=0,a1=0,a2=0, c0=0,c1=0,c2=0;
    #pragma unroll
    for (int j = 0; j < 3; ++j) {
        const float4 v  = s40[j*64 + lane];
        const float4 w2 = s41[j*64 + lane];
        a0 += v.x*wgt[j][0][0] + v.y*wgt[j][1][0] + v.z*wgt[j][2][0] + v.w*wgt[j][3][0];
        a1 += v.x*wgt[j][0][1] + v.y*wgt[j][1][1] + v.z*wgt[j][2][1] + v.w*wgt[j][3][1];
        a2 += v.x*wgt[j][0][2] + v.y*wgt[j][1][2] + v.z*wgt[j][2][2] + v.w*wgt[j][3][2];
        c0 += w2.x*wgt[j][0][0] + w2.y*wgt[j][1][0] + w2.z*wgt[j][2][0] + w2.w*wgt[j][3][0];
        c1 += w2.x*wgt[j][0][1] + w2.y*wgt[j][1][1] + w2.z*wgt[j][2][1] + w2.w*wgt[j][3][1];
        c2 += w2.x*wgt[j][0][2] + w2.y*wgt[j][1][2] + w2.z*wgt[j][2][2] + w2.w*wgt[j][3][2];
    }
    a0 = wred64(a0); a1 = wred64(a1); a2 = wred64(a2);
    c0 = wred64(c0); c1 = wred64(c1); c2 = wred64(c2);
    if (lane == 0) {
        dst0[0] = a0; dst0[1] = a1; dst0[2] = a2;
        dst1[0] = c0; dst1[1] = c1; dst1[2] = c2;
    }
}

// ---------- Kernel C: slot_gate_prob ----------------------------------------
__global__ __launch_bounds__(256) void kC(
    const float* __restrict__ cls, const float* __restrict__ WgW,
    const float* __restrict__ bgW, const float* __restrict__ bgate,
    const int* __restrict__ nptr, const int* __restrict__ ptrpos,
    float* __restrict__ out)
{
    const int lane = threadIdx.x & 63, wid = threadIdx.x >> 6;
    const int idx = blockIdx.x * 4 + wid;       // b*SS + m
    if (idx >= BB*SS) return;
    const int b = idx / SS, m = idx % SS;

    float s0, s1, s2;
    if (m < nptr[b]) {
        const int s = ptrpos[b*SS + m];
        const float4* c4 = (const float4*)(cls + (size_t)b * DD);
        float a0 = 0.f, a1 = 0.f, a2 = 0.f;
        #pragma unroll
        for (int j = 0; j < 3; ++j) {
            const float4 v = c4[j*64 + lane];
            const float* wp = WgW + ((size_t)s*DD + j*256 + lane*4) * 3;
            a0 += v.x*wp[0] + v.y*wp[3] + v.z*wp[6] + v.w*wp[9];
            a1 += v.x*wp[1] + v.y*wp[4] + v.z*wp[7] + v.w*wp[10];
            a2 += v.x*wp[2] + v.y*wp[5] + v.z*wp[8] + v.w*wp[11];
        }
        a0 = wred64(a0); a1 = wred64(a1); a2 = wred64(a2);
        s0 = a0 + bgW[s*3+0] + bgate[0];
        s1 = a1 + bgW[s*3+1] + bgate[1];
        s2 = a2 + bgW[s*3+2] + bgate[2];
    } else {
        s0 = bgate[0]; s1 = bgate[1]; s2 = bgate[2];
    }
    if (lane == 0) {
        const float mx = fmaxf(s0, fmaxf(s1, s2));
        const float e0 = expf(s0 - mx), e1 = expf(s1 - mx), e2 = expf(s2 - mx);
        const float inv = 1.f / (e0 + e1 + e2);
        float* o = out + O_GATE + (size_t)idx * NGATEc;
        o[0] = e0*inv; o[1] = e1*inv; o[2] = e2*inv;
    }
}

// ---------- Kernel E: softmax in place over L=512 ---------------------------
__global__ __launch_bounds__(256) void kE(
    const int* __restrict__ nsel, float* __restrict__ out)
{
    const int idx = blockIdx.x;             // b*SS + k
    const int b = idx / SS, k = idx % SS;
    const int tid = threadIdx.x;
    float* outs = out + O_SPROB + (size_t)idx * LL;
    float* oute = out + O_EPROB + (size_t)idx * LL;

    if (k >= nsel[b]) {                     // softmax(zeros) = 1/L exactly
        const float u = 1.0f / LL;
        outs[tid] = u; outs[tid + 256] = u;
        oute[tid] = u; oute[tid + 256] = u;
        return;
    }
    const int lane = tid & 63, wid = tid >> 6;
    __shared__ float rmax[2][4], rsum[2][4];

    const float s0 = outs[tid], s1 = outs[tid + 256];
    const float t0 = oute[tid], t1 = oute[tid + 256];

    float ms = fmaxf(s0, s1), me = fmaxf(t0, t1);
    #pragma unroll
    for (int o = 32; o; o >>= 1) { ms = fmaxf(ms, __shfl_xor(ms, o)); me = fmaxf(me, __shfl_xor(me, o)); }
    if (lane == 0) { rmax[0][wid] = ms; rmax[1][wid] = me; }
    __syncthreads();
    ms = fmaxf(fmaxf(rmax[0][0], rmax[0][1]), fmaxf(rmax[0][2], rmax[0][3]));
    me = fmaxf(fmaxf(rmax[1][0], rmax[1][1]), fmaxf(rmax[1][2], rmax[1][3]));

    const float e0 = expf(s0 - ms), e1 = expf(s1 - ms);
    const float f0 = expf(t0 - me), f1 = expf(t1 - me);
    float sa = e0 + e1, sb = f0 + f1;
    #pragma unroll
    for (int o = 32; o; o >>= 1) { sa += __shfl_xor(sa, o); sb += __shfl_xor(sb, o); }
    if (lane == 0) { rsum[0][wid] = sa; rsum[1][wid] = sb; }
    __syncthreads();
    const float inva = 1.f / (rsum[0][0] + rsum[0][1] + rsum[0][2] + rsum[0][3]);
    const float invb = 1.f / (rsum[1][0] + rsum[1][1] + rsum[1][2] + rsum[1][3]);

    outs[tid] = e0 * inva; outs[tid + 256] = e1 * inva;
    oute[tid] = f0 * invb; oute[tid + 256] = f1 * invb;
}

extern "C" void kernel_launch(void* const* d_in, const int* in_sizes, int n_in,
                              void* d_out, int out_size, void* d_ws, size_t ws_size,
                              hipStream_t stream)
{
    const float* H      = (const float*)d_in[0];
    const float* cls    = (const float*)d_in[1];
    const float* Wdom   = (const float*)d_in[2];
    const float* bdom   = (const float*)d_in[3];
    const float* Wslot  = (const float*)d_in[4];
    const float* bslot  = (const float*)d_in[5];
    const float* Wg     = (const float*)d_in[6];
    const float* bg     = (const float*)d_in[7];
    const float* Wgate  = (const float*)d_in[8];
    const float* bgate  = (const float*)d_in[9];
    const float* Wstart = (const float*)d_in[10];
    // d_in[11] b_start: constant per softmax row -> softmax-invariant, unused
    const float* Wend   = (const float*)d_in[12];
    // d_in[13] b_end: unused (same reason)
    const int* sp = (const int*)d_in[14];
    const int* sg = (const int*)d_in[15];

    float* out = (float*)d_out;
    float* wsf = (float*)d_ws;
    float* WgW = wsf;
    float* bgW = wsf + WS_BGW;
    ushort* Wb = (ushort*)(wsf + WS_WB);
    int* ipart  = (int*)(wsf + WS_INT);
    int* nptr   = ipart;
    int* nsel   = ipart + 64;
    int* ptrpos = ipart + 128;
    int* selpos = ptrpos + BB*SS;
    int* s2r    = selpos + BB*SS;

    kA<<<BB + WBF, 256, 0, stream>>>(cls, Wdom, bdom, Wslot, bslot, sp, sg, out,
                                     nptr, nsel, ptrpos, selpos, s2r,
                                     Wstart, Wend, Wb);
    kBG<<<GB + KB_BLOCKS, 256, 0, stream>>>(H, Wb, nsel, s2r, out,
                                            Wg, bg, Wgate, WgW, bgW);
    kC<<<(BB*SS) / 4, 256, 0, stream>>>(cls, WgW, bgW, bgate, nptr, ptrpos, out);
    kE<<<BB * SS, 256, 0, stream>>>(nsel, out);
}